// Round 2
// baseline (6654.465 us; speedup 1.0000x reference)
//
#include <hip/hip_runtime.h>

#define BB 8
#define NN 8192
#define NPOINT 2048
#define NSAMPLE 64
#define CIN 64
#define RADIUS 0.2f
#define R2 (RADIUS * RADIUS)

// d_out layout (flat floats, reference return order)
#define OFF_NEWXYZ 0
#define OFF_FEAT (BB * NPOINT * 3)
#define OFF_INDS (OFF_FEAT + BB * NPOINT * 128)
#define OFF_IDX (OFF_INDS + BB * NPOINT)

// ---------------------------------------------------------------------------
// Kernel 1: new_xyz gather + inds passthrough + ball query (wave per query)
// ---------------------------------------------------------------------------
__global__ __launch_bounds__(256) void ballq_kernel(
    const float* __restrict__ xyz, const int* __restrict__ inds,
    float* __restrict__ out) {
  const int wq = (blockIdx.x * 256 + threadIdx.x) >> 6;  // query id
  const int lane = threadIdx.x & 63;
  const int b = wq / NPOINT;
  const int s = wq - b * NPOINT;

  const float* xb = xyz + (size_t)b * NN * 3;
  const int ind = inds[b * NPOINT + s];
  const float cx = xb[ind * 3 + 0];
  const float cy = xb[ind * 3 + 1];
  const float cz = xb[ind * 3 + 2];

  if (lane == 0) {
    out[OFF_NEWXYZ + (size_t)wq * 3 + 0] = cx;
    out[OFF_NEWXYZ + (size_t)wq * 3 + 1] = cy;
    out[OFF_NEWXYZ + (size_t)wq * 3 + 2] = cz;
    out[OFF_INDS + wq] = (float)ind;
  }

  // match reference distance formula: qq + nn - 2*dot
  const float qq = cx * cx + cy * cy + cz * cz;
  float* myidx = out + OFF_IDX + (size_t)wq * NSAMPLE;

  int cnt = 0;
  int first = -1;
  for (int j0 = 0; j0 < NN; j0 += 64) {
    const int j = j0 + lane;
    const float px = xb[j * 3 + 0];
    const float py = xb[j * 3 + 1];
    const float pz = xb[j * 3 + 2];
    const float nn = px * px + py * py + pz * pz;
    const float dot = cx * px + cy * py + cz * pz;
    const float d2 = qq + nn - 2.0f * dot;
    const bool hit = d2 < R2;
    const unsigned long long m = __ballot(hit);
    if (hit) {
      const int pos = cnt + (int)__popcll(m & ((1ull << lane) - 1ull));
      if (pos < NSAMPLE) myidx[pos] = (float)j;
    }
    if (first < 0 && m != 0ull) first = j0 + __builtin_ctzll(m);
    cnt += (int)__popcll(m);
    if (cnt >= NSAMPLE) break;
  }
  if (first < 0) first = NN - 1;  // unreachable (center is its own hit)
  if (lane >= cnt) myidx[lane] = (float)first;  // pad with first hit
}

// ---------------------------------------------------------------------------
// Kernel 2: group -> 3-layer MLP -> maxpool. Wave per query; lane = sample.
// Streaming/accumulator-major form: peak live set = 64 acc + 64 prev-layer
// activations (~140 VGPR) -> no spills. Weights via wave-uniform s_loads.
// __launch_bounds__(256,3): VGPR cap ~168 so the compiler does NOT pick a
// low-VGPR/spill-heavy allocation (round-1 kernel got 72 VGPR + AGPR spills).
// ---------------------------------------------------------------------------
__global__ __launch_bounds__(256, 3) void mlp_kernel(
    const float* __restrict__ xyz, const float* __restrict__ features,
    const int* __restrict__ inds,
    const float* __restrict__ w0, const float* __restrict__ s0,
    const float* __restrict__ t0, const float* __restrict__ w1,
    const float* __restrict__ s1, const float* __restrict__ t1,
    const float* __restrict__ w2, const float* __restrict__ s2,
    const float* __restrict__ t2, float* __restrict__ out) {
  const int wq = (blockIdx.x * 256 + threadIdx.x) >> 6;  // query id
  const int lane = threadIdx.x & 63;                     // sample id
  const int b = wq / NPOINT;
  const int s = wq - b * NPOINT;

  const float* xb = xyz + (size_t)b * NN * 3;
  const int ind = inds[b * NPOINT + s];
  const float cx = xb[ind * 3 + 0];
  const float cy = xb[ind * 3 + 1];
  const float cz = xb[ind * 3 + 2];

  const int id = (int)out[OFF_IDX + (size_t)wq * NSAMPLE + lane];

  // ---- layer 0: 67 -> 64 (stream inputs, 64 accumulators) ----
  float acc[64];   // doubles as h0, then as layer-2 accumulator
  float acc1[64];  // layer-1 accumulator, then h1
#pragma unroll
  for (int d = 0; d < 64; ++d) acc[d] = 0.0f;

  {
    const float xin0 = (xb[id * 3 + 0] - cx) * (1.0f / RADIUS);
    const float xin1 = (xb[id * 3 + 1] - cy) * (1.0f / RADIUS);
    const float xin2 = (xb[id * 3 + 2] - cz) * (1.0f / RADIUS);
#pragma unroll
    for (int d = 0; d < 64; ++d) acc[d] = fmaf(xin0, w0[0 * 64 + d], acc[d]);
#pragma unroll
    for (int d = 0; d < 64; ++d) acc[d] = fmaf(xin1, w0[1 * 64 + d], acc[d]);
#pragma unroll
    for (int d = 0; d < 64; ++d) acc[d] = fmaf(xin2, w0[2 * 64 + d], acc[d]);

    const float4* frow =
        (const float4*)(features + ((size_t)b * NN + (size_t)id) * CIN);
#pragma unroll
    for (int c4 = 0; c4 < 16; ++c4) {
      const float4 f = frow[c4];
      const float* wr = w0 + (3 + 4 * c4) * 64;
#pragma unroll
      for (int d = 0; d < 64; ++d) acc[d] = fmaf(f.x, wr[d], acc[d]);
#pragma unroll
      for (int d = 0; d < 64; ++d) acc[d] = fmaf(f.y, wr[64 + d], acc[d]);
#pragma unroll
      for (int d = 0; d < 64; ++d) acc[d] = fmaf(f.z, wr[128 + d], acc[d]);
#pragma unroll
      for (int d = 0; d < 64; ++d) acc[d] = fmaf(f.w, wr[192 + d], acc[d]);
    }
#pragma unroll
    for (int d = 0; d < 64; ++d)
      acc[d] = fmaxf(fmaf(acc[d], s0[d], t0[d]), 0.0f);  // acc = h0
  }

  // ---- layer 1: 64 -> 64 ----
#pragma unroll
  for (int d = 0; d < 64; ++d) acc1[d] = 0.0f;
#pragma unroll
  for (int c = 0; c < 64; ++c) {
    const float hc = acc[c];
    const float* wr = w1 + c * 64;
#pragma unroll
    for (int d = 0; d < 64; ++d) acc1[d] = fmaf(hc, wr[d], acc1[d]);
  }
#pragma unroll
  for (int d = 0; d < 64; ++d)
    acc1[d] = fmaxf(fmaf(acc1[d], s1[d], t1[d]), 0.0f);  // acc1 = h1

  // ---- layer 2: 64 -> 128 in two 64-output halves, fused maxpool ----
  float* of = out + OFF_FEAT + (size_t)wq * 128;
#pragma unroll
  for (int half = 0; half < 2; ++half) {
#pragma unroll
    for (int d = 0; d < 64; ++d) acc[d] = 0.0f;
#pragma unroll
    for (int c = 0; c < 64; ++c) {
      const float hc = acc1[c];
      const float* wr = w2 + c * 128 + half * 64;
#pragma unroll
      for (int d = 0; d < 64; ++d) acc[d] = fmaf(hc, wr[d], acc[d]);
    }
    const float* sp = s2 + half * 64;
    const float* tp = t2 + half * 64;
#pragma unroll
    for (int d = 0; d < 64; ++d)
      acc[d] = fmaxf(fmaf(acc[d], sp[d], tp[d]), 0.0f);

    // Split-butterfly transpose-reduce over the 64 lanes (samples):
    // after the loop, acc[0] on lane l = max over samples of channel l.
    // Invariant: entering stride s, acc[i] (i<2s) holds channel
    // (lane & ~(2s-1) & 63)|i reduced over lanes differing in bits > s.
#pragma unroll
    for (int st = 32; st >= 1; st >>= 1) {
      const bool hi = (lane & st) != 0;
#pragma unroll
      for (int i = 0; i < st; ++i) {
        const float sendv = hi ? acc[i] : acc[i + st];
        const float recv = __shfl_xor(sendv, st, 64);
        const float mine = hi ? acc[i + st] : acc[i];
        acc[i] = fmaxf(mine, recv);
      }
    }
    of[half * 64 + lane] = acc[0];
  }
}

extern "C" void kernel_launch(void* const* d_in, const int* in_sizes, int n_in,
                              void* d_out, int out_size, void* d_ws,
                              size_t ws_size, hipStream_t stream) {
  const float* xyz = (const float*)d_in[0];
  const float* features = (const float*)d_in[1];
  const int* inds = (const int*)d_in[2];
  const float* w0 = (const float*)d_in[3];
  const float* s0 = (const float*)d_in[4];
  const float* t0 = (const float*)d_in[5];
  const float* w1 = (const float*)d_in[6];
  const float* s1 = (const float*)d_in[7];
  const float* t1 = (const float*)d_in[8];
  const float* w2 = (const float*)d_in[9];
  const float* s2 = (const float*)d_in[10];
  const float* t2 = (const float*)d_in[11];
  float* out = (float*)d_out;

  const int nquery = BB * NPOINT;  // 16384 queries
  const int blocks = nquery / 4;   // 4 waves (queries) per 256-thread block

  ballq_kernel<<<blocks, 256, 0, stream>>>(xyz, inds, out);
  mlp_kernel<<<blocks, 256, 0, stream>>>(xyz, features, inds, w0, s0, t0, w1,
                                         s1, t1, w2, s2, t2, out);
}

// Round 3
// 237.329 us; speedup vs baseline: 28.0390x; 28.0390x over previous
//
#include <hip/hip_runtime.h>

#define BB 8
#define NN 8192
#define NPOINT 2048
#define NSAMPLE 64
#define CIN 64
#define RADIUS 0.2f
#define R2 (RADIUS * RADIUS)

// d_out layout (flat floats, reference return order)
#define OFF_NEWXYZ 0
#define OFF_FEAT (BB * NPOINT * 3)
#define OFF_INDS (OFF_FEAT + BB * NPOINT * 128)
#define OFF_IDX (OFF_INDS + BB * NPOINT)

typedef _Float16 half8 __attribute__((ext_vector_type(8)));
typedef _Float16 half4 __attribute__((ext_vector_type(4)));
typedef float floatx16 __attribute__((ext_vector_type(16)));

// ---- LDS layout (elements of _Float16). All K-contiguous ("[outer][k]") so
// every MFMA fragment is one ds_read_b128. Pitches padded off power-of-2.
#define P0 104  // pitch for WT0 / Xbuf (K0 = 80 = 64 feat + 3 xyz + 13 zero)
#define P1 72   // pitch for WT1 / WT2 / Hbuf (K = 64)
#define WT0_OFF 0
#define WT1_OFF (WT0_OFF + 64 * P0)   // 6656
#define WT2_OFF (WT1_OFF + 64 * P1)   // 11264
#define X_OFF (WT2_OFF + 128 * P1)    // 20480
#define H_OFF (X_OFF + 64 * P0)       // 27136
#define LDS_TOTAL (H_OFF + 64 * P1)   // 31744 halves = 63488 B (2 blocks/CU)

#define QPB 32  // queries per block; grid = 16384/QPB = 512 = 2 blocks/CU

// ---------------------------------------------------------------------------
// Kernel 1: new_xyz gather + inds passthrough + ball query (wave per query)
// (unchanged from round 1 — ~50 us; optimize later once mlp is fixed)
// ---------------------------------------------------------------------------
__global__ __launch_bounds__(256) void ballq_kernel(
    const float* __restrict__ xyz, const int* __restrict__ inds,
    float* __restrict__ out) {
  const int wq = (blockIdx.x * 256 + threadIdx.x) >> 6;  // query id
  const int lane = threadIdx.x & 63;
  const int b = wq / NPOINT;
  const int s = wq - b * NPOINT;

  const float* xb = xyz + (size_t)b * NN * 3;
  const int ind = inds[b * NPOINT + s];
  const float cx = xb[ind * 3 + 0];
  const float cy = xb[ind * 3 + 1];
  const float cz = xb[ind * 3 + 2];

  if (lane == 0) {
    out[OFF_NEWXYZ + (size_t)wq * 3 + 0] = cx;
    out[OFF_NEWXYZ + (size_t)wq * 3 + 1] = cy;
    out[OFF_NEWXYZ + (size_t)wq * 3 + 2] = cz;
    out[OFF_INDS + wq] = (float)ind;
  }

  const float qq = cx * cx + cy * cy + cz * cz;
  float* myidx = out + OFF_IDX + (size_t)wq * NSAMPLE;

  int cnt = 0;
  int first = -1;
  for (int j0 = 0; j0 < NN; j0 += 64) {
    const int j = j0 + lane;
    const float px = xb[j * 3 + 0];
    const float py = xb[j * 3 + 1];
    const float pz = xb[j * 3 + 2];
    const float nn = px * px + py * py + pz * pz;
    const float dot = cx * px + cy * py + cz * pz;
    const float d2 = qq + nn - 2.0f * dot;
    const bool hit = d2 < R2;
    const unsigned long long m = __ballot(hit);
    if (hit) {
      const int pos = cnt + (int)__popcll(m & ((1ull << lane) - 1ull));
      if (pos < NSAMPLE) myidx[pos] = (float)j;
    }
    if (first < 0 && m != 0ull) first = j0 + __builtin_ctzll(m);
    cnt += (int)__popcll(m);
    if (cnt >= NSAMPLE) break;
  }
  if (first < 0) first = NN - 1;
  if (lane >= cnt) myidx[lane] = (float)first;
}

// ---------------------------------------------------------------------------
// Kernel 2: MFMA MLP. Block = 4 waves cooperating on one query at a time.
// L0/L1 transposed (H^T = W^T X^T): wave = (mt,nt) quadrant of 64x64, C/D
// reg-quads pack into half4 row-major [sample][d] writes (next layer's A).
// L2 normal (Y = H1 W2^T): wave = 32-channel column tile, lane owns one d2
// -> maxpool is 15 v_max + one shfl_xor(32).
// ---------------------------------------------------------------------------
__global__ __launch_bounds__(256, 2) void mlp_mfma(
    const float* __restrict__ xyz, const float* __restrict__ features,
    const int* __restrict__ inds,
    const float* __restrict__ w0, const float* __restrict__ s0,
    const float* __restrict__ t0, const float* __restrict__ w1,
    const float* __restrict__ s1, const float* __restrict__ t1,
    const float* __restrict__ w2, const float* __restrict__ s2,
    const float* __restrict__ t2, float* __restrict__ out) {
  __shared__ _Float16 sm[LDS_TOTAL];
  const int tid = threadIdx.x;
  const int w = tid >> 6;      // wave id 0..3
  const int l = tid & 63;      // lane
  const int h5 = l >> 5;       // lane half
  const int l31 = l & 31;
  const int mt = w >> 1, nt = w & 1;  // quadrant for L0/L1
  const int koff = h5 * 8;            // A/B frag k-offset within a k-step

  // ---- stage weights to LDS, transposed+fp16, once per block ----
  {
    const int d = tid >> 2, q4 = tid & 3;
    // WT0[d][c]: c<64 -> w0 row 3+c (features); 64..66 -> rows 0..2 (xyz);
    // 67..79 -> 0 (K padding). X uses the same channel order.
#pragma unroll
    for (int j = 0; j < 20; ++j) {
      const int c = q4 * 20 + j;
      float v = 0.0f;
      if (c < 64) v = w0[(3 + c) * 64 + d];
      else if (c < 67) v = w0[(c - 64) * 64 + d];
      sm[WT0_OFF + d * P0 + c] = (_Float16)v;
    }
#pragma unroll
    for (int j = 0; j < 16; ++j) {
      const int c = q4 * 16 + j;
      sm[WT1_OFF + d * P1 + c] = (_Float16)w1[c * 64 + d];
    }
    const int d2 = tid >> 1, h2 = tid & 1;
#pragma unroll
    for (int j = 0; j < 32; ++j) {
      const int c = h2 * 32 + j;
      sm[WT2_OFF + d2 * P1 + c] = (_Float16)w2[c * 128 + d2];
    }
    if (tid < 64) {  // zero X K-padding once (never overwritten)
#pragma unroll
      for (int c = 67; c < 80; ++c) sm[X_OFF + tid * P0 + c] = (_Float16)0.0f;
    }
  }
  __syncthreads();

  // ---- hoist weight fragments + scale/shift into registers (block-invariant)
  half8 a0f[5], a1f[4], b2f[4];
#pragma unroll
  for (int ks = 0; ks < 5; ++ks)
    a0f[ks] = *(const half8*)&sm[WT0_OFF + (mt * 32 + l31) * P0 + ks * 16 + koff];
#pragma unroll
  for (int ks = 0; ks < 4; ++ks)
    a1f[ks] = *(const half8*)&sm[WT1_OFF + (mt * 32 + l31) * P1 + ks * 16 + koff];
#pragma unroll
  for (int ks = 0; ks < 4; ++ks)
    b2f[ks] = *(const half8*)&sm[WT2_OFF + (w * 32 + l31) * P1 + ks * 16 + koff];

  float s0v[16], t0v[16], s1v[16], t1v[16];
#pragma unroll
  for (int reg = 0; reg < 16; ++reg) {
    const int r = (reg & 3) + 8 * (reg >> 2) + 4 * h5;  // C/D row map 32x32
    const int d = mt * 32 + r;
    s0v[reg] = s0[d]; t0v[reg] = t0[d];
    s1v[reg] = s1[d]; t1v[reg] = t1[d];
  }
  const float s2L = s2[w * 32 + l31];
  const float t2L = t2[w * 32 + l31];

  const int q0 = blockIdx.x * QPB;
  for (int qi = 0; qi < QPB; ++qi) {
    const int q = q0 + qi;
    const int b = q >> 11;  // NPOINT = 2048
    __syncthreads();        // prev iteration's readers of Xbuf/Hbuf are done

    // ---- stage X: thread = (sample s = tid>>2, 16-feature chunk ch) ----
    {
      const int s = tid >> 2, ch = tid & 3;
      const int idxs = (int)out[OFF_IDX + (size_t)q * NSAMPLE + s];
      const float4* f4 =
          (const float4*)(features + ((size_t)(b * NN) + idxs) * CIN + ch * 16);
#pragma unroll
      for (int u = 0; u < 2; ++u) {
        const float4 fa = f4[u * 2 + 0];
        const float4 fb = f4[u * 2 + 1];
        half8 hv;
        hv[0] = (_Float16)fa.x; hv[1] = (_Float16)fa.y;
        hv[2] = (_Float16)fa.z; hv[3] = (_Float16)fa.w;
        hv[4] = (_Float16)fb.x; hv[5] = (_Float16)fb.y;
        hv[6] = (_Float16)fb.z; hv[7] = (_Float16)fb.w;
        *(half8*)&sm[X_OFF + s * P0 + ch * 16 + u * 8] = hv;
      }
      if (ch == 0) {  // xyz delta channels 64..66
        const int sq = q & (NPOINT - 1);
        const int ind = inds[b * NPOINT + sq];
        const float* xb = xyz + (size_t)b * NN * 3;
        const float cx = xb[ind * 3 + 0], cy = xb[ind * 3 + 1],
                    cz = xb[ind * 3 + 2];
        sm[X_OFF + s * P0 + 64] = (_Float16)((xb[idxs * 3 + 0] - cx) * 5.0f);
        sm[X_OFF + s * P0 + 65] = (_Float16)((xb[idxs * 3 + 1] - cy) * 5.0f);
        sm[X_OFF + s * P0 + 66] = (_Float16)((xb[idxs * 3 + 2] - cz) * 5.0f);
      }
    }
    __syncthreads();

    // ---- L0: H0^T = W0^T X^T (M=d0, N=sample, K=80) ----
    {
      floatx16 acc;
#pragma unroll
      for (int i = 0; i < 16; ++i) acc[i] = 0.0f;
      const _Float16* bp = &sm[X_OFF + (nt * 32 + l31) * P0 + koff];
#pragma unroll
      for (int ks = 0; ks < 5; ++ks)
        acc = __builtin_amdgcn_mfma_f32_32x32x16_f16(
            a0f[ks], *(const half8*)(bp + ks * 16), acc, 0, 0, 0);
      const int sampleL = nt * 32 + l31;
#pragma unroll
      for (int g = 0; g < 4; ++g) {
        half4 hv;
#pragma unroll
        for (int r = 0; r < 4; ++r) {
          const int reg = g * 4 + r;
          hv[r] = (_Float16)fmaxf(fmaf(acc[reg], s0v[reg], t0v[reg]), 0.0f);
        }
        *(half4*)&sm[H_OFF + sampleL * P1 + mt * 32 + 8 * g + 4 * h5] = hv;
      }
    }
    __syncthreads();

    // ---- L1: H1^T = W1^T H0^T (K=64), write H1 into Xbuf[sample][d1] ----
    {
      floatx16 acc;
#pragma unroll
      for (int i = 0; i < 16; ++i) acc[i] = 0.0f;
      const _Float16* bp = &sm[H_OFF + (nt * 32 + l31) * P1 + koff];
#pragma unroll
      for (int ks = 0; ks < 4; ++ks)
        acc = __builtin_amdgcn_mfma_f32_32x32x16_f16(
            a1f[ks], *(const half8*)(bp + ks * 16), acc, 0, 0, 0);
      const int sampleL = nt * 32 + l31;
#pragma unroll
      for (int g = 0; g < 4; ++g) {
        half4 hv;
#pragma unroll
        for (int r = 0; r < 4; ++r) {
          const int reg = g * 4 + r;
          hv[r] = (_Float16)fmaxf(fmaf(acc[reg], s1v[reg], t1v[reg]), 0.0f);
        }
        *(half4*)&sm[X_OFF + sampleL * P0 + mt * 32 + 8 * g + 4 * h5] = hv;
      }
    }
    __syncthreads();

    // ---- L2: Y = H1 W2^T (M=sample, N=d2, K=64) + fused maxpool ----
    {
      floatx16 aA, aB;
#pragma unroll
      for (int i = 0; i < 16; ++i) { aA[i] = 0.0f; aB[i] = 0.0f; }
      const _Float16* hpA = &sm[X_OFF + l31 * P0 + koff];         // samples 0..31
      const _Float16* hpB = &sm[X_OFF + (32 + l31) * P0 + koff];  // samples 32..63
#pragma unroll
      for (int ks = 0; ks < 4; ++ks) {
        aA = __builtin_amdgcn_mfma_f32_32x32x16_f16(
            *(const half8*)(hpA + ks * 16), b2f[ks], aA, 0, 0, 0);
        aB = __builtin_amdgcn_mfma_f32_32x32x16_f16(
            *(const half8*)(hpB + ks * 16), b2f[ks], aB, 0, 0, 0);
      }
      float mx = 0.0f;  // relu floor
#pragma unroll
      for (int reg = 0; reg < 16; ++reg) {
        const float vA = fmaxf(fmaf(aA[reg], s2L, t2L), 0.0f);
        const float vB = fmaxf(fmaf(aB[reg], s2L, t2L), 0.0f);
        mx = fmaxf(mx, fmaxf(vA, vB));
      }
      mx = fmaxf(mx, __shfl_xor(mx, 32, 64));  // merge complementary row sets
      if (l < 32) out[OFF_FEAT + (size_t)q * 128 + w * 32 + l] = mx;
    }
  }
}

extern "C" void kernel_launch(void* const* d_in, const int* in_sizes, int n_in,
                              void* d_out, int out_size, void* d_ws,
                              size_t ws_size, hipStream_t stream) {
  const float* xyz = (const float*)d_in[0];
  const float* features = (const float*)d_in[1];
  const int* inds = (const int*)d_in[2];
  const float* w0 = (const float*)d_in[3];
  const float* s0 = (const float*)d_in[4];
  const float* t0 = (const float*)d_in[5];
  const float* w1 = (const float*)d_in[6];
  const float* s1 = (const float*)d_in[7];
  const float* t1 = (const float*)d_in[8];
  const float* w2 = (const float*)d_in[9];
  const float* s2 = (const float*)d_in[10];
  const float* t2 = (const float*)d_in[11];
  float* out = (float*)d_out;

  const int nquery = BB * NPOINT;  // 16384
  ballq_kernel<<<nquery / 4, 256, 0, stream>>>(xyz, inds, out);
  mlp_mfma<<<nquery / QPB, 256, 0, stream>>>(xyz, features, inds, w0, s0, t0,
                                             w1, s1, t1, w2, s2, t2, out);
}

// Round 6
// 187.964 us; speedup vs baseline: 35.4028x; 1.2626x over previous
//
#include <hip/hip_runtime.h>

#define BB 8
#define NN 8192
#define NPOINT 2048
#define NSAMPLE 64
#define CIN 64
#define RADIUS 0.2f
#define R2 (RADIUS * RADIUS)

// d_out layout (flat floats, reference return order)
#define OFF_NEWXYZ 0
#define OFF_FEAT (BB * NPOINT * 3)
#define OFF_INDS (OFF_FEAT + BB * NPOINT * 128)
#define OFF_IDX (OFF_INDS + BB * NPOINT)

typedef _Float16 half8 __attribute__((ext_vector_type(8)));
typedef float floatx16 __attribute__((ext_vector_type(16)));

// Per-wave LDS slice (halves). P0=88 (K0=80 + pad, stride 176B = 12 banks mod
// 32 -> conflict-free b128). P1=72 (144B = 4 banks mod 32 -> conflict-free).
#define P0 88
#define P1 72
#define X_LOC 0
#define H_LOC (64 * P0)                 // 5632
#define XH_WAVE (64 * P0 + 64 * P1)     // 10240 halves = 20480 B per wave
// Weight staging regions (block-shared, overlap the wave slices, used once
// before any X/H writes):
#define WT0_S 0
#define WT1_S (64 * P0)
#define WT2_S (64 * P0 + 64 * P1)       // 10240..19456 (fits in 20480*2)

#define QPW 8  // queries per wave

// ---------------------------------------------------------------------------
// Kernel 1: new_xyz gather + inds passthrough + ball query.
// Wave per query, 4 candidates per lane per iteration (k-major order keeps
// exact first-NSAMPLE-in-point-order semantics via 4 sequential ballots).
// ---------------------------------------------------------------------------
__global__ __launch_bounds__(256) void ballq_kernel(
    const float* __restrict__ xyz, const int* __restrict__ inds,
    float* __restrict__ out) {
  const int wq = (blockIdx.x * 256 + threadIdx.x) >> 6;  // query id
  const int lane = threadIdx.x & 63;
  const int b = wq >> 11;  // NPOINT = 2048

  const float* xb = xyz + (size_t)b * NN * 3;
  const int ind = inds[wq];
  const float cx = xb[ind * 3 + 0];
  const float cy = xb[ind * 3 + 1];
  const float cz = xb[ind * 3 + 2];

  if (lane == 0) {
    out[OFF_NEWXYZ + (size_t)wq * 3 + 0] = cx;
    out[OFF_NEWXYZ + (size_t)wq * 3 + 1] = cy;
    out[OFF_NEWXYZ + (size_t)wq * 3 + 2] = cz;
    out[OFF_INDS + wq] = (float)ind;
  }

  const float qq = cx * cx + cy * cy + cz * cz;  // match reference formula
  float* myidx = out + OFF_IDX + (size_t)wq * NSAMPLE;

  int cnt = 0;
  for (int j0 = 0; j0 < NN; j0 += 256) {
    float px[4], py[4], pz[4];
#pragma unroll
    for (int k = 0; k < 4; ++k) {  // 12 independent loads up front
      const float* p = xb + (size_t)(j0 + k * 64 + lane) * 3;
      px[k] = p[0];
      py[k] = p[1];
      pz[k] = p[2];
    }
#pragma unroll
    for (int k = 0; k < 4; ++k) {
      const float nn = px[k] * px[k] + py[k] * py[k] + pz[k] * pz[k];
      const float dot = cx * px[k] + cy * py[k] + cz * pz[k];
      const bool hit = (qq + nn - 2.0f * dot) < R2;
      const unsigned long long m = __ballot(hit);
      if (hit) {
        const int pos = cnt + (int)__popcll(m & ((1ull << lane) - 1ull));
        if (pos < NSAMPLE) myidx[pos] = (float)(j0 + k * 64 + lane);
      }
      cnt += (int)__popcll(m);
    }
    if (cnt >= NSAMPLE) break;
  }
  // Pad: center point always hits itself -> cnt >= 1 -> myidx[0] valid.
  const float f0 = myidx[0];
  if (lane >= cnt) myidx[lane] = f0;
}

// ---------------------------------------------------------------------------
// Kernel 2: barrier-free MFMA MLP. 128-thread block = 2 independent waves;
// each wave owns one query at a time in a private LDS slice. Weights are
// register-resident B-fragments (scale s* folded in; t0 folded in as bias
// channel 67 of X; t1/t2 are column-indexed -> 2+4 VGPRs).
// Orientation: H[sample][d] = X[sample][c] * W[c][d] -> A = activations
// (ds_read_b128 row fragments), B = weights (registers), C cols = d (lane),
// C rows = samples -> L2 maxpool is a register reduction + 1 shuffle.
// ---------------------------------------------------------------------------
__global__ __launch_bounds__(128, 2) void mlp_mfma(
    const float* __restrict__ xyz, const float* __restrict__ features,
    const int* __restrict__ inds,
    const float* __restrict__ w0, const float* __restrict__ s0,
    const float* __restrict__ t0, const float* __restrict__ w1,
    const float* __restrict__ s1, const float* __restrict__ t1,
    const float* __restrict__ w2, const float* __restrict__ s2,
    const float* __restrict__ t2, float* __restrict__ out) {
  __shared__ _Float16 sm[2 * XH_WAVE];  // 40960 B -> 4 blocks/CU = 8 waves/CU
  const int tid = threadIdx.x;
  const int w = tid >> 6;
  const int l = tid & 63;
  const int l31 = l & 31;
  const int h5 = l >> 5;
  const int koff = h5 * 8;  // fragment k-offset in halves

  // ---- stage folded weights into fragment-layout LDS (block-wide, once) ----
  {
    const int d = tid >> 1, hf = tid & 1;
    const float sd0 = s0[d], td0 = t0[d], sd1 = s1[d];
#pragma unroll
    for (int j = 0; j < 44; ++j) {
      const int c = hf * 44 + j;
      float v = 0.0f;
      if (c < 64) v = w0[(3 + c) * 64 + d] * sd0;        // feature channels
      else if (c < 67) v = w0[(c - 64) * 64 + d] * sd0;  // xyz channels
      else if (c == 67) v = td0;                         // bias channel
      sm[WT0_S + d * P0 + c] = (_Float16)v;
    }
#pragma unroll
    for (int j = 0; j < 32; ++j) {
      const int c = hf * 32 + j;
      sm[WT1_S + d * P1 + c] = (_Float16)(w1[c * 64 + d] * sd1);
    }
    const int ch = tid;  // 0..127
    const float sch = s2[ch];
#pragma unroll
    for (int c = 0; c < 64; ++c)
      sm[WT2_S + ch * P1 + c] = (_Float16)(w2[c * 128 + ch] * sch);
  }
  __syncthreads();

  // ---- hoist weight fragments + t vectors into registers ----
  half8 b0f[2][5], b1f[2][4], b2f[4][4];
#pragma unroll
  for (int nt = 0; nt < 2; ++nt)
#pragma unroll
    for (int ks = 0; ks < 5; ++ks)
      b0f[nt][ks] =
          *(const half8*)&sm[WT0_S + (nt * 32 + l31) * P0 + ks * 16 + koff];
#pragma unroll
  for (int nt = 0; nt < 2; ++nt)
#pragma unroll
    for (int ks = 0; ks < 4; ++ks)
      b1f[nt][ks] =
          *(const half8*)&sm[WT1_S + (nt * 32 + l31) * P1 + ks * 16 + koff];
#pragma unroll
  for (int ct = 0; ct < 4; ++ct)
#pragma unroll
    for (int ks = 0; ks < 4; ++ks)
      b2f[ct][ks] =
          *(const half8*)&sm[WT2_S + (ct * 32 + l31) * P1 + ks * 16 + koff];
  const float t1v0 = t1[l31];
  const float t1v1 = t1[32 + l31];
  float t2v[4];
#pragma unroll
  for (int ct = 0; ct < 4; ++ct) t2v[ct] = t2[ct * 32 + l31];
  __syncthreads();  // all fragment reads done before X/H overwrite the region

  _Float16* xbuf = sm + w * XH_WAVE + X_LOC;
  _Float16* hbuf = sm + w * XH_WAVE + H_LOC;
  // zero X K-pad halves 72..79 once (64..71 rewritten per query)
  {
    half8 z = {};
    *(half8*)&xbuf[l * P0 + 72] = z;
  }

  const int wq0 = (blockIdx.x * 2 + w) * QPW;
#pragma unroll 1
  for (int qi = 0; qi < QPW; ++qi) {
    const int q = wq0 + qi;
    const int b = q >> 11;

    // ---- gather + stage X (lane = sample) ----
    const int idxs = (int)out[OFF_IDX + (size_t)q * NSAMPLE + l];
    const float* xb = xyz + (size_t)b * NN * 3;
    const int ind = inds[q];
    const float cx = xb[ind * 3 + 0], cy = xb[ind * 3 + 1],
                cz = xb[ind * 3 + 2];
    const float ppx = xb[idxs * 3 + 0], ppy = xb[idxs * 3 + 1],
                ppz = xb[idxs * 3 + 2];
    const float4* fr =
        (const float4*)(features + ((size_t)b * NN + (size_t)idxs) * CIN);
    float4 f[16];
#pragma unroll
    for (int u = 0; u < 16; ++u) f[u] = fr[u];
#pragma unroll
    for (int u = 0; u < 8; ++u) {
      half8 hv;
      hv[0] = (_Float16)f[2 * u].x;
      hv[1] = (_Float16)f[2 * u].y;
      hv[2] = (_Float16)f[2 * u].z;
      hv[3] = (_Float16)f[2 * u].w;
      hv[4] = (_Float16)f[2 * u + 1].x;
      hv[5] = (_Float16)f[2 * u + 1].y;
      hv[6] = (_Float16)f[2 * u + 1].z;
      hv[7] = (_Float16)f[2 * u + 1].w;
      *(half8*)&xbuf[l * P0 + u * 8] = hv;
    }
    {
      half8 xv = {};
      xv[0] = (_Float16)((ppx - cx) * 5.0f);
      xv[1] = (_Float16)((ppy - cy) * 5.0f);
      xv[2] = (_Float16)((ppz - cz) * 5.0f);
      xv[3] = (_Float16)1.0f;  // bias channel 67
      *(half8*)&xbuf[l * P0 + 64] = xv;
    }

    // ---- L0: H0 = relu(X @ W0' + t0) (K=80, bias via channel 67) ----
    {
      half8 xa[2][5];
#pragma unroll
      for (int st = 0; st < 2; ++st)
#pragma unroll
        for (int ks = 0; ks < 5; ++ks)
          xa[st][ks] =
              *(const half8*)&xbuf[(st * 32 + l31) * P0 + ks * 16 + koff];
#pragma unroll
      for (int nt = 0; nt < 2; ++nt)
#pragma unroll
        for (int st = 0; st < 2; ++st) {
          floatx16 acc;
#pragma unroll
          for (int i = 0; i < 16; ++i) acc[i] = 0.0f;
#pragma unroll
          for (int ks = 0; ks < 5; ++ks)
            acc = __builtin_amdgcn_mfma_f32_32x32x16_f16(xa[st][ks],
                                                         b0f[nt][ks], acc,
                                                         0, 0, 0);
#pragma unroll
          for (int reg = 0; reg < 16; ++reg) {
            const int row = st * 32 + (reg & 3) + 8 * (reg >> 2) + 4 * h5;
            hbuf[row * P1 + nt * 32 + l31] =
                (_Float16)fmaxf(acc[reg], 0.0f);
          }
        }
    }

    // ---- L1: H1 = relu(H0 @ W1' + t1), written into xbuf cols 0..63 ----
    {
      half8 ha[2][4];
#pragma unroll
      for (int st = 0; st < 2; ++st)
#pragma unroll
        for (int ks = 0; ks < 4; ++ks)
          ha[st][ks] =
              *(const half8*)&hbuf[(st * 32 + l31) * P1 + ks * 16 + koff];
#pragma unroll
      for (int nt = 0; nt < 2; ++nt) {
        const float tt = nt ? t1v1 : t1v0;
#pragma unroll
        for (int st = 0; st < 2; ++st) {
          floatx16 acc;
#pragma unroll
          for (int i = 0; i < 16; ++i) acc[i] = 0.0f;
#pragma unroll
          for (int ks = 0; ks < 4; ++ks)
            acc = __builtin_amdgcn_mfma_f32_32x32x16_f16(ha[st][ks],
                                                         b1f[nt][ks], acc,
                                                         0, 0, 0);
#pragma unroll
          for (int reg = 0; reg < 16; ++reg) {
            const int row = st * 32 + (reg & 3) + 8 * (reg >> 2) + 4 * h5;
            xbuf[row * P0 + nt * 32 + l31] =
                (_Float16)fmaxf(acc[reg] + tt, 0.0f);
          }
        }
      }
    }

    // ---- L2: Y = relu(H1 @ W2' + t2), fused maxpool over samples ----
    {
      half8 h1a[2][4];
#pragma unroll
      for (int st = 0; st < 2; ++st)
#pragma unroll
        for (int ks = 0; ks < 4; ++ks)
          h1a[st][ks] =
              *(const half8*)&xbuf[(st * 32 + l31) * P0 + ks * 16 + koff];
#pragma unroll
      for (int ct = 0; ct < 4; ++ct) {
        floatx16 aA, aB;
#pragma unroll
        for (int i = 0; i < 16; ++i) {
          aA[i] = 0.0f;
          aB[i] = 0.0f;
        }
#pragma unroll
        for (int ks = 0; ks < 4; ++ks) {
          aA = __builtin_amdgcn_mfma_f32_32x32x16_f16(h1a[0][ks], b2f[ct][ks],
                                                      aA, 0, 0, 0);
          aB = __builtin_amdgcn_mfma_f32_32x32x16_f16(h1a[1][ks], b2f[ct][ks],
                                                      aB, 0, 0, 0);
        }
        float m = fmaxf(aA[0], aB[0]);
#pragma unroll
        for (int i = 1; i < 16; ++i) m = fmaxf(m, fmaxf(aA[i], aB[i]));
        float v = fmaxf(m + t2v[ct], 0.0f);  // relu(max+t) == max(relu(+t))
        v = fmaxf(v, __shfl_xor(v, 32, 64));  // merge complementary row halves
        if (l < 32) out[OFF_FEAT + (size_t)q * 128 + ct * 32 + l] = v;
      }
    }
  }
}

extern "C" void kernel_launch(void* const* d_in, const int* in_sizes, int n_in,
                              void* d_out, int out_size, void* d_ws,
                              size_t ws_size, hipStream_t stream) {
  const float* xyz = (const float*)d_in[0];
  const float* features = (const float*)d_in[1];
  const int* inds = (const int*)d_in[2];
  const float* w0 = (const float*)d_in[3];
  const float* s0 = (const float*)d_in[4];
  const float* t0 = (const float*)d_in[5];
  const float* w1 = (const float*)d_in[6];
  const float* s1 = (const float*)d_in[7];
  const float* t1 = (const float*)d_in[8];
  const float* w2 = (const float*)d_in[9];
  const float* s2 = (const float*)d_in[10];
  const float* t2 = (const float*)d_in[11];
  float* out = (float*)d_out;

  const int nquery = BB * NPOINT;  // 16384
  ballq_kernel<<<nquery / 4, 256, 0, stream>>>(xyz, inds, out);
  // 2 waves/block * QPW queries each -> 1024 blocks
  mlp_mfma<<<nquery / (2 * QPW), 128, 0, stream>>>(
      xyz, features, inds, w0, s0, t0, w1, s1, t1, w2, s2, t2, out);
}